// Round 1
// baseline (131.618 us; speedup 1.0000x reference)
//
#include <hip/hip_runtime.h>
#include <math.h>

// Problem constants
#define BB    16
#define DIMM  1024
#define TN    2048
#define NBINS 625

// Output layout (floats, concatenated in reference return order)
//   zero:       4
//   feat_t:     B*DIM*T = 33,554,432
//   perplexity: 4
//   ind_t:      B*4*T   = 131,072
static constexpr size_t OUT_ZERO = 0;
static constexpr size_t OUT_FEAT = 4;
static constexpr size_t OUT_PERP = 4 + (size_t)BB * DIMM * TN;
static constexpr size_t OUT_IND  = OUT_PERP + 4;

// Workspace layout (bytes):
//   counts : 4*625 floats      @ 0        (10 KB, padded to 16 KB)
//   partial: 524288 doubles    @ 16384    (4 MB)   [b][tt][ch][c][256]
//   qbuf   : 262144 floats     @ 4210688  (1 MB)   [b*T + t][8]
// total ~5.2 MB

// ---------------------------------------------------------------------------
// A1: partial projection z. Each block: one (b, t-tile of 256, 256-row chunk).
// x read exactly once, coalesced along t. f64 accumulate to match np-f64 ref.
// ---------------------------------------------------------------------------
__global__ __launch_bounds__(256) void gfsq_a1(const float* __restrict__ x,
                                               const float* __restrict__ w_in,
                                               double* __restrict__ partial) {
  const int ch  = blockIdx.x;   // 0..3  (row chunk of 256; g = ch>>1)
  const int tt  = blockIdx.y;   // 0..7
  const int b   = blockIdx.z;   // 0..15
  const int tid = threadIdx.x;
  const int g   = ch >> 1;
  const int d0  = (ch & 1) * 256;

  __shared__ float wl[256][4];
  #pragma unroll
  for (int c = 0; c < 4; ++c)
    wl[tid][c] = w_in[g * 2048 + c * 512 + d0 + tid];
  __syncthreads();

  const int t = tt * 256 + tid;
  const float* xp = x + ((size_t)b * DIMM + (size_t)ch * 256) * TN + t;

  double a0 = 0.0, a1 = 0.0, a2 = 0.0, a3 = 0.0;
  #pragma unroll 8
  for (int r = 0; r < 256; ++r) {
    double xv = (double)xp[(size_t)r * TN];
    a0 += (double)wl[r][0] * xv;
    a1 += (double)wl[r][1] * xv;
    a2 += (double)wl[r][2] * xv;
    a3 += (double)wl[r][3] * xv;
  }

  double* pp = partial + (((size_t)(b * 8 + tt) * 4 + ch) * 4) * 256 + tid;
  pp[0]   = a0;
  pp[256] = a1;
  pp[512] = a2;
  pp[768] = a3;
}

// ---------------------------------------------------------------------------
// A2: finalize z, residual-FSQ quantize (f64 chain, matches np), write ind,
// histogram atomics, and q (f32, exact multiples of 0.125) for the out-proj.
// ---------------------------------------------------------------------------
__global__ __launch_bounds__(256) void gfsq_a2(const double* __restrict__ partial,
                                               const float* __restrict__ b_in,
                                               float* __restrict__ qbuf,
                                               float* __restrict__ counts,
                                               float* __restrict__ out) {
  const int id = blockIdx.x * 256 + threadIdx.x;  // (b, t)
  const int b  = id >> 11;
  const int t  = id & 2047;
  const int tt = t >> 8;
  const int tl = t & 255;

  const double half_l = (5.0 - 1.0) * (1.0 + 1e-3) / 2.0;  // 2.002, match np expr
  const int basis[4] = {1, 5, 25, 125};

  const double* pp = partial + ((size_t)(b * 8 + tt) * 16) * 256 + tl;

  float q[8];
  #pragma unroll
  for (int g = 0; g < 2; ++g) {
    int idx0 = 0, idx1 = 0;
    #pragma unroll
    for (int c = 0; c < 4; ++c) {
      double z = pp[((g * 2 + 0) * 4 + c) * 256]
               + pp[((g * 2 + 1) * 4 + c) * 256]
               + (double)b_in[g * 4 + c];
      // step 0: s = 1
      double n0 = rint(tanh(z) * half_l);          // in {-2..2}
      double r1 = z - 0.5 * n0;                    // residual - codes*s
      // step 1: s = 0.25 -> input = r1/0.25 = 4*r1 (exact)
      double n1 = rint(tanh(4.0 * r1) * half_l);
      q[g * 4 + c] = (float)(0.5 * n0 + 0.125 * n1);  // exact in f32
      idx0 += ((int)n0 + 2) * basis[c];
      idx1 += ((int)n1 + 2) * basis[c];
    }
    // ind_t[b, j, t], j = g*2 + r  (g-major)
    out[OUT_IND + ((size_t)b * 4 + g * 2 + 0) * TN + t] = (float)idx0;
    out[OUT_IND + ((size_t)b * 4 + g * 2 + 1) * TN + t] = (float)idx1;
    atomicAdd(&counts[(g * 2 + 0) * NBINS + idx0], 1.0f);
    atomicAdd(&counts[(g * 2 + 1) * NBINS + idx1], 1.0f);
  }

  float4* qp = (float4*)(qbuf + (size_t)id * 8);
  qp[0] = make_float4(q[0], q[1], q[2], q[3]);
  qp[1] = make_float4(q[4], q[5], q[6], q[7]);
}

// ---------------------------------------------------------------------------
// B: out-projection feat_t[b, dim, t] = sum_c q[b,t,g,c]*w_out[g,d,c] + b_out.
// w_out flat index == dim*4+c; b_out flat == dim. One block: 128 dims x 256 t.
// ---------------------------------------------------------------------------
__global__ __launch_bounds__(256) void gfsq_b(const float* __restrict__ qbuf,
                                              const float* __restrict__ w_out,
                                              const float* __restrict__ b_out,
                                              float* __restrict__ out) {
  const int dch = blockIdx.x;   // 0..7 (128 dims each; g = dch>>2)
  const int tt  = blockIdx.y;   // 0..7
  const int b   = blockIdx.z;   // 0..15
  const int tid = threadIdx.x;

  __shared__ float4 wl[128];
  __shared__ float  bl[128];
  if (tid < 128) {
    wl[tid] = ((const float4*)w_out)[dch * 128 + tid];
    bl[tid] = b_out[dch * 128 + tid];
  }
  __syncthreads();

  const int t = tt * 256 + tid;
  const float4* qp = (const float4*)(qbuf + ((size_t)b * TN + t) * 8);
  const float4 qg = (dch < 4) ? qp[0] : qp[1];

  float* op = out + OUT_FEAT + ((size_t)b * DIMM + (size_t)dch * 128) * TN + t;
  #pragma unroll 4
  for (int dd = 0; dd < 128; ++dd) {
    float4 w = wl[dd];
    op[(size_t)dd * TN] = bl[dd] + w.x * qg.x + w.y * qg.y + w.z * qg.z + w.w * qg.w;
  }
}

// ---------------------------------------------------------------------------
// P: perplexity from counts (one wave per codebook j), plus the zero output.
// ---------------------------------------------------------------------------
__global__ __launch_bounds__(256) void gfsq_p(const float* __restrict__ counts,
                                              float* __restrict__ out) {
  const int tid  = threadIdx.x;
  const int j    = tid >> 6;    // wave id = codebook row
  const int lane = tid & 63;

  double s = 0.0;
  for (int i = lane; i < NBINS; i += 64) s += (double)counts[j * NBINS + i];
  #pragma unroll
  for (int off = 32; off; off >>= 1) s += __shfl_xor(s, off, 64);
  const double tot = s / 32768.0;  // sum of e_mean (== 1.0 exactly)

  double h = 0.0;
  for (int i = lane; i < NBINS; i += 64) {
    double e  = (double)counts[j * NBINS + i] / 32768.0;
    double e2 = e / (tot + 1e-5);
    h += e2 * log(e2 + 1e-5);
  }
  #pragma unroll
  for (int off = 32; off; off >>= 1) h += __shfl_xor(h, off, 64);

  if (lane == 0) out[OUT_PERP + j] = (float)exp(-h);
  if (tid < 4)  out[OUT_ZERO + tid] = 0.0f;
}

// ---------------------------------------------------------------------------
extern "C" void kernel_launch(void* const* d_in, const int* in_sizes, int n_in,
                              void* d_out, int out_size, void* d_ws, size_t ws_size,
                              hipStream_t stream) {
  (void)in_sizes; (void)n_in; (void)out_size; (void)ws_size;

  const float* x     = (const float*)d_in[0];
  const float* w_in  = (const float*)d_in[1];
  const float* b_in  = (const float*)d_in[2];
  const float* w_out = (const float*)d_in[3];
  const float* b_out = (const float*)d_in[4];
  float* out = (float*)d_out;

  char* ws = (char*)d_ws;
  float*  counts  = (float*)ws;                         // 2500 floats
  double* partial = (double*)(ws + 16384);              // 524288 doubles
  float*  qbuf    = (float*)(ws + 16384 + 4194304);     // 262144 floats

  hipMemsetAsync(counts, 0, 4 * NBINS * sizeof(float), stream);
  gfsq_a1<<<dim3(4, 8, 16), 256, 0, stream>>>(x, w_in, partial);
  gfsq_a2<<<128, 256, 0, stream>>>(partial, b_in, qbuf, counts, out);
  gfsq_b<<<dim3(8, 8, 16), 256, 0, stream>>>(qbuf, w_out, b_out, out);
  gfsq_p<<<1, 256, 0, stream>>>(counts, out);
}

// Round 2
// 127.040 us; speedup vs baseline: 1.0360x; 1.0360x over previous
//
#include <hip/hip_runtime.h>
#include <math.h>

// Problem constants
#define BB    16
#define DIMM  1024
#define TN    2048
#define NBINS 625

// Output layout (floats, concatenated in reference return order)
//   zero:       4
//   feat_t:     B*DIM*T = 33,554,432
//   perplexity: 4
//   ind_t:      B*4*T   = 131,072
static constexpr size_t OUT_ZERO = 0;
static constexpr size_t OUT_FEAT = 4;
static constexpr size_t OUT_PERP = 4 + (size_t)BB * DIMM * TN;
static constexpr size_t OUT_IND  = OUT_PERP + 4;

// Workspace layout (bytes):
//   counts : 4*625 floats      @ 0        (10 KB, padded to 16 KB)
//   partial: 524288 doubles    @ 16384    (4 MB)   [b][tt][ch][c][256]
//   qbuf   : 262144 floats     @ 4210688  (1 MB)   [b*T + t][8]
// total ~5.2 MB

// ---------------------------------------------------------------------------
// A1: partial projection z. Each block: one (b, t-tile of 256, 256-row chunk).
// x read exactly once, coalesced along t. f64 accumulate to match np-f64 ref.
// Block (0,0,0) also zeroes the histogram counts (replaces a ~77us memset
// node; a1 completes before a2's atomics since they are separate dispatches).
// ---------------------------------------------------------------------------
__global__ __launch_bounds__(256) void gfsq_a1(const float* __restrict__ x,
                                               const float* __restrict__ w_in,
                                               double* __restrict__ partial,
                                               float* __restrict__ counts) {
  const int ch  = blockIdx.x;   // 0..3  (row chunk of 256; g = ch>>1)
  const int tt  = blockIdx.y;   // 0..7
  const int b   = blockIdx.z;   // 0..15
  const int tid = threadIdx.x;
  const int g   = ch >> 1;
  const int d0  = (ch & 1) * 256;

  if (ch == 0 && tt == 0 && b == 0) {
    for (int i = tid; i < 4 * NBINS; i += 256) counts[i] = 0.0f;
  }

  __shared__ float wl[256][4];
  #pragma unroll
  for (int c = 0; c < 4; ++c)
    wl[tid][c] = w_in[g * 2048 + c * 512 + d0 + tid];
  __syncthreads();

  const int t = tt * 256 + tid;
  const float* xp = x + ((size_t)b * DIMM + (size_t)ch * 256) * TN + t;

  double a0 = 0.0, a1 = 0.0, a2 = 0.0, a3 = 0.0;
  #pragma unroll 8
  for (int r = 0; r < 256; ++r) {
    double xv = (double)xp[(size_t)r * TN];
    a0 += (double)wl[r][0] * xv;
    a1 += (double)wl[r][1] * xv;
    a2 += (double)wl[r][2] * xv;
    a3 += (double)wl[r][3] * xv;
  }

  double* pp = partial + (((size_t)(b * 8 + tt) * 4 + ch) * 4) * 256 + tid;
  pp[0]   = a0;
  pp[256] = a1;
  pp[512] = a2;
  pp[768] = a3;
}

// ---------------------------------------------------------------------------
// A2: finalize z, residual-FSQ quantize (f64 chain, matches np), write ind,
// histogram atomics, and q (f32, exact multiples of 0.125) for the out-proj.
// ---------------------------------------------------------------------------
__global__ __launch_bounds__(256) void gfsq_a2(const double* __restrict__ partial,
                                               const float* __restrict__ b_in,
                                               float* __restrict__ qbuf,
                                               float* __restrict__ counts,
                                               float* __restrict__ out) {
  const int id = blockIdx.x * 256 + threadIdx.x;  // (b, t)
  const int b  = id >> 11;
  const int t  = id & 2047;
  const int tt = t >> 8;
  const int tl = t & 255;

  const double half_l = (5.0 - 1.0) * (1.0 + 1e-3) / 2.0;  // 2.002, match np expr
  const int basis[4] = {1, 5, 25, 125};

  const double* pp = partial + ((size_t)(b * 8 + tt) * 16) * 256 + tl;

  float q[8];
  #pragma unroll
  for (int g = 0; g < 2; ++g) {
    int idx0 = 0, idx1 = 0;
    #pragma unroll
    for (int c = 0; c < 4; ++c) {
      double z = pp[((g * 2 + 0) * 4 + c) * 256]
               + pp[((g * 2 + 1) * 4 + c) * 256]
               + (double)b_in[g * 4 + c];
      // step 0: s = 1
      double n0 = rint(tanh(z) * half_l);          // in {-2..2}
      double r1 = z - 0.5 * n0;                    // residual - codes*s
      // step 1: s = 0.25 -> input = r1/0.25 = 4*r1 (exact)
      double n1 = rint(tanh(4.0 * r1) * half_l);
      q[g * 4 + c] = (float)(0.5 * n0 + 0.125 * n1);  // exact in f32
      idx0 += ((int)n0 + 2) * basis[c];
      idx1 += ((int)n1 + 2) * basis[c];
    }
    // ind_t[b, j, t], j = g*2 + r  (g-major)
    out[OUT_IND + ((size_t)b * 4 + g * 2 + 0) * TN + t] = (float)idx0;
    out[OUT_IND + ((size_t)b * 4 + g * 2 + 1) * TN + t] = (float)idx1;
    atomicAdd(&counts[(g * 2 + 0) * NBINS + idx0], 1.0f);
    atomicAdd(&counts[(g * 2 + 1) * NBINS + idx1], 1.0f);
  }

  float4* qp = (float4*)(qbuf + (size_t)id * 8);
  qp[0] = make_float4(q[0], q[1], q[2], q[3]);
  qp[1] = make_float4(q[4], q[5], q[6], q[7]);
}

// ---------------------------------------------------------------------------
// B: out-projection feat_t[b, dim, t] = sum_c q[b,t,g,c]*w_out[g,d,c] + b_out.
// w_out flat index == dim*4+c; b_out flat == dim. One block: 128 dims x 256 t.
// ---------------------------------------------------------------------------
__global__ __launch_bounds__(256) void gfsq_b(const float* __restrict__ qbuf,
                                              const float* __restrict__ w_out,
                                              const float* __restrict__ b_out,
                                              float* __restrict__ out) {
  const int dch = blockIdx.x;   // 0..7 (128 dims each; g = dch>>2)
  const int tt  = blockIdx.y;   // 0..7
  const int b   = blockIdx.z;   // 0..15
  const int tid = threadIdx.x;

  __shared__ float4 wl[128];
  __shared__ float  bl[128];
  if (tid < 128) {
    wl[tid] = ((const float4*)w_out)[dch * 128 + tid];
    bl[tid] = b_out[dch * 128 + tid];
  }
  __syncthreads();

  const int t = tt * 256 + tid;
  const float4* qp = (const float4*)(qbuf + ((size_t)b * TN + t) * 8);
  const float4 qg = (dch < 4) ? qp[0] : qp[1];

  float* op = out + OUT_FEAT + ((size_t)b * DIMM + (size_t)dch * 128) * TN + t;
  #pragma unroll 4
  for (int dd = 0; dd < 128; ++dd) {
    float4 w = wl[dd];
    op[(size_t)dd * TN] = bl[dd] + w.x * qg.x + w.y * qg.y + w.z * qg.z + w.w * qg.w;
  }
}

// ---------------------------------------------------------------------------
// P: perplexity from counts (one wave per codebook j), plus the zero output.
// ---------------------------------------------------------------------------
__global__ __launch_bounds__(256) void gfsq_p(const float* __restrict__ counts,
                                              float* __restrict__ out) {
  const int tid  = threadIdx.x;
  const int j    = tid >> 6;    // wave id = codebook row
  const int lane = tid & 63;

  double s = 0.0;
  for (int i = lane; i < NBINS; i += 64) s += (double)counts[j * NBINS + i];
  #pragma unroll
  for (int off = 32; off; off >>= 1) s += __shfl_xor(s, off, 64);
  const double tot = s / 32768.0;  // sum of e_mean (== 1.0 exactly)

  double h = 0.0;
  for (int i = lane; i < NBINS; i += 64) {
    double e  = (double)counts[j * NBINS + i] / 32768.0;
    double e2 = e / (tot + 1e-5);
    h += e2 * log(e2 + 1e-5);
  }
  #pragma unroll
  for (int off = 32; off; off >>= 1) h += __shfl_xor(h, off, 64);

  if (lane == 0) out[OUT_PERP + j] = (float)exp(-h);
  if (tid < 4)  out[OUT_ZERO + tid] = 0.0f;
}

// ---------------------------------------------------------------------------
extern "C" void kernel_launch(void* const* d_in, const int* in_sizes, int n_in,
                              void* d_out, int out_size, void* d_ws, size_t ws_size,
                              hipStream_t stream) {
  (void)in_sizes; (void)n_in; (void)out_size; (void)ws_size;

  const float* x     = (const float*)d_in[0];
  const float* w_in  = (const float*)d_in[1];
  const float* b_in  = (const float*)d_in[2];
  const float* w_out = (const float*)d_in[3];
  const float* b_out = (const float*)d_in[4];
  float* out = (float*)d_out;

  char* ws = (char*)d_ws;
  float*  counts  = (float*)ws;                         // 2500 floats
  double* partial = (double*)(ws + 16384);              // 524288 doubles
  float*  qbuf    = (float*)(ws + 16384 + 4194304);     // 262144 floats

  gfsq_a1<<<dim3(4, 8, 16), 256, 0, stream>>>(x, w_in, partial, counts);
  gfsq_a2<<<128, 256, 0, stream>>>(partial, b_in, qbuf, counts, out);
  gfsq_b<<<dim3(8, 8, 16), 256, 0, stream>>>(qbuf, w_out, b_out, out);
  gfsq_p<<<1, 256, 0, stream>>>(counts, out);
}

// Round 3
// 108.688 us; speedup vs baseline: 1.2110x; 1.1689x over previous
//
#include <hip/hip_runtime.h>
#include <math.h>

// Problem constants
#define BB    16
#define DIMM  1024
#define TN    2048
#define NBINS 625

// Output layout (floats, concatenated in reference return order)
//   zero:       4
//   feat_t:     B*DIM*T = 33,554,432
//   perplexity: 4
//   ind_t:      B*4*T   = 131,072
static constexpr size_t OUT_ZERO = 0;
static constexpr size_t OUT_FEAT = 4;
static constexpr size_t OUT_PERP = 4 + (size_t)BB * DIMM * TN;
static constexpr size_t OUT_IND  = OUT_PERP + 4;

// Workspace layout (bytes):
//   counts : 4*625 floats      @ 0        (10 KB, padded to 16 KB)
//   partial: 1048576 doubles   @ 16384    (8 MB)   [b][tt][ch(8)][c(4)][256]
//   qbuf   : 262144 floats     @ 8404992  (1 MB)   [b*T + t][8]

// ---------------------------------------------------------------------------
// A1: partial projection z. Each block: one (b, t-tile of 256, 128-row chunk).
// x read exactly once, coalesced along t. f64 accumulate to match np-f64 ref.
// 1024 blocks -> 4 blocks/CU for read-latency hiding.
// Block (0,0,0) also zeroes the histogram counts (a1 completes before a2's
// atomics since they are separate dispatches on the same stream).
// ---------------------------------------------------------------------------
__global__ __launch_bounds__(256) void gfsq_a1(const float* __restrict__ x,
                                               const float* __restrict__ w_in,
                                               double* __restrict__ partial,
                                               float* __restrict__ counts) {
  const int ch  = blockIdx.x;   // 0..7  (row chunk of 128; g = ch>>2)
  const int tt  = blockIdx.y;   // 0..7
  const int b   = blockIdx.z;   // 0..15
  const int tid = threadIdx.x;
  const int g   = ch >> 2;
  const int d0  = (ch & 3) * 128;

  if (ch == 0 && tt == 0 && b == 0) {
    for (int i = tid; i < 4 * NBINS; i += 256) counts[i] = 0.0f;
  }

  __shared__ float wl[128][4];
  if (tid < 128) {
    #pragma unroll
    for (int c = 0; c < 4; ++c)
      wl[tid][c] = w_in[g * 2048 + c * 512 + d0 + tid];
  }
  __syncthreads();

  const int t = tt * 256 + tid;
  const float* xp = x + ((size_t)b * DIMM + (size_t)ch * 128) * TN + t;

  double a0 = 0.0, a1 = 0.0, a2 = 0.0, a3 = 0.0;
  #pragma unroll 8
  for (int r = 0; r < 128; ++r) {
    double xv = (double)xp[(size_t)r * TN];
    a0 += (double)wl[r][0] * xv;
    a1 += (double)wl[r][1] * xv;
    a2 += (double)wl[r][2] * xv;
    a3 += (double)wl[r][3] * xv;
  }

  double* pp = partial + (((size_t)(b * 8 + tt) * 8 + ch) * 4) * 256 + tid;
  pp[0]   = a0;
  pp[256] = a1;
  pp[512] = a2;
  pp[768] = a3;
}

// ---------------------------------------------------------------------------
// A2: finalize z, residual-FSQ quantize (f64 chain, matches np), write ind,
// histogram atomics, and q (f32, exact multiples of 0.125) for the out-proj.
// 64-thread blocks x 512 -> tanh work spread over all 256 CUs.
// ---------------------------------------------------------------------------
__global__ __launch_bounds__(64) void gfsq_a2(const double* __restrict__ partial,
                                              const float* __restrict__ b_in,
                                              float* __restrict__ qbuf,
                                              float* __restrict__ counts,
                                              float* __restrict__ out) {
  const int id = blockIdx.x * 64 + threadIdx.x;  // (b, t)
  const int b  = id >> 11;
  const int t  = id & 2047;
  const int tt = t >> 8;
  const int tl = t & 255;

  const double half_l = (5.0 - 1.0) * (1.0 + 1e-3) / 2.0;  // 2.002, match np expr
  const int basis[4] = {1, 5, 25, 125};

  const double* pp = partial + ((size_t)(b * 8 + tt) * 32) * 256 + tl;

  float q[8];
  #pragma unroll
  for (int g = 0; g < 2; ++g) {
    int idx0 = 0, idx1 = 0;
    #pragma unroll
    for (int c = 0; c < 4; ++c) {
      double z = (double)b_in[g * 4 + c];
      #pragma unroll
      for (int h = 0; h < 4; ++h)
        z += pp[((g * 4 + h) * 4 + c) * 256];
      // step 0: s = 1
      double n0 = rint(tanh(z) * half_l);          // in {-2..2}
      double r1 = z - 0.5 * n0;                    // residual - codes*s
      // step 1: s = 0.25 -> input = r1/0.25 = 4*r1 (exact)
      double n1 = rint(tanh(4.0 * r1) * half_l);
      q[g * 4 + c] = (float)(0.5 * n0 + 0.125 * n1);  // exact in f32
      idx0 += ((int)n0 + 2) * basis[c];
      idx1 += ((int)n1 + 2) * basis[c];
    }
    // ind_t[b, j, t], j = g*2 + r  (g-major)
    out[OUT_IND + ((size_t)b * 4 + g * 2 + 0) * TN + t] = (float)idx0;
    out[OUT_IND + ((size_t)b * 4 + g * 2 + 1) * TN + t] = (float)idx1;
    atomicAdd(&counts[(g * 2 + 0) * NBINS + idx0], 1.0f);
    atomicAdd(&counts[(g * 2 + 1) * NBINS + idx1], 1.0f);
  }

  float4* qp = (float4*)(qbuf + (size_t)id * 8);
  qp[0] = make_float4(q[0], q[1], q[2], q[3]);
  qp[1] = make_float4(q[4], q[5], q[6], q[7]);
}

// ---------------------------------------------------------------------------
// B: out-projection feat_t[b, dim, t] = sum_c q[b,t,g,c]*w_out[g,d,c] + b_out.
// w_out flat index == dim*4+c; b_out flat == dim. One block: 128 dims x 256 t.
// blockIdx.x == 8 is a single extra block doing the perplexity reduction
// (counts are final: the a2 dispatch completed before b started).
// ---------------------------------------------------------------------------
__global__ __launch_bounds__(256) void gfsq_b(const float* __restrict__ qbuf,
                                              const float* __restrict__ w_out,
                                              const float* __restrict__ b_out,
                                              const float* __restrict__ counts,
                                              float* __restrict__ out) {
  const int dch = blockIdx.x;   // 0..7 (128 dims each; g = dch>>2); 8 = perp
  const int tt  = blockIdx.y;   // 0..7
  const int b   = blockIdx.z;   // 0..15
  const int tid = threadIdx.x;

  if (dch == 8) {
    if (tt != 0 || b != 0) return;
    const int j    = tid >> 6;    // wave id = codebook row
    const int lane = tid & 63;

    double s = 0.0;
    for (int i = lane; i < NBINS; i += 64) s += (double)counts[j * NBINS + i];
    #pragma unroll
    for (int off = 32; off; off >>= 1) s += __shfl_xor(s, off, 64);
    const double tot = s / 32768.0;  // sum of e_mean (== 1.0 exactly)

    double h = 0.0;
    for (int i = lane; i < NBINS; i += 64) {
      double e  = (double)counts[j * NBINS + i] / 32768.0;
      double e2 = e / (tot + 1e-5);
      h += e2 * log(e2 + 1e-5);
    }
    #pragma unroll
    for (int off = 32; off; off >>= 1) h += __shfl_xor(h, off, 64);

    if (lane == 0) out[OUT_PERP + j] = (float)exp(-h);
    if (tid < 4)  out[OUT_ZERO + tid] = 0.0f;
    return;
  }

  __shared__ float4 wl[128];
  __shared__ float  bl[128];
  if (tid < 128) {
    wl[tid] = ((const float4*)w_out)[dch * 128 + tid];
    bl[tid] = b_out[dch * 128 + tid];
  }
  __syncthreads();

  const int t = tt * 256 + tid;
  const float4* qp = (const float4*)(qbuf + ((size_t)b * TN + t) * 8);
  const float4 qg = (dch < 4) ? qp[0] : qp[1];

  float* op = out + OUT_FEAT + ((size_t)b * DIMM + (size_t)dch * 128) * TN + t;
  #pragma unroll 4
  for (int dd = 0; dd < 128; ++dd) {
    float4 w = wl[dd];
    op[(size_t)dd * TN] = bl[dd] + w.x * qg.x + w.y * qg.y + w.z * qg.z + w.w * qg.w;
  }
}

// ---------------------------------------------------------------------------
extern "C" void kernel_launch(void* const* d_in, const int* in_sizes, int n_in,
                              void* d_out, int out_size, void* d_ws, size_t ws_size,
                              hipStream_t stream) {
  (void)in_sizes; (void)n_in; (void)out_size; (void)ws_size;

  const float* x     = (const float*)d_in[0];
  const float* w_in  = (const float*)d_in[1];
  const float* b_in  = (const float*)d_in[2];
  const float* w_out = (const float*)d_in[3];
  const float* b_out = (const float*)d_in[4];
  float* out = (float*)d_out;

  char* ws = (char*)d_ws;
  float*  counts  = (float*)ws;                         // 2500 floats
  double* partial = (double*)(ws + 16384);              // 1048576 doubles
  float*  qbuf    = (float*)(ws + 16384 + 8388608);     // 262144 floats

  gfsq_a1<<<dim3(8, 8, 16), 256, 0, stream>>>(x, w_in, partial, counts);
  gfsq_a2<<<512, 64, 0, stream>>>(partial, b_in, qbuf, counts, out);
  gfsq_b<<<dim3(9, 8, 16), 256, 0, stream>>>(qbuf, w_out, b_out, counts, out);
}

// Round 4
// 92.173 us; speedup vs baseline: 1.4279x; 1.1792x over previous
//
#include <hip/hip_runtime.h>
#include <math.h>

// Problem constants
#define BB    16
#define DIMM  1024
#define TN    2048
#define NBINS 625

// Output layout (floats, concatenated in reference return order)
//   zero: 4 | feat_t: B*DIM*T | perplexity: 4 | ind_t: B*4*T
static constexpr size_t OUT_ZERO = 0;
static constexpr size_t OUT_FEAT = 4;
static constexpr size_t OUT_PERP = 4 + (size_t)BB * DIMM * TN;
static constexpr size_t OUT_IND  = OUT_PERP + 4;

// Workspace: qbuf only — 262144 floats @ 0 (1 MB), [b*T + t][8] (g-major float4 pairs)

// ---------------------------------------------------------------------------
// K1: fused projection + residual-FSQ. One block = (b, 64-t tile).
// Wave w (of 4) accumulates rows [w*256, w*256+256) in f64 (matches np ref);
// LDS reduce across waves; waves 0/1 run the f64 tanh/rint chain per group,
// write ind (exact ints) and qbuf (exact multiples of 0.125).
// x is read exactly once, coalesced along t (256B per wave per row).
// ---------------------------------------------------------------------------
__global__ __launch_bounds__(256) void gfsq_k1(const float* __restrict__ x,
                                               const float* __restrict__ w_in,
                                               const float* __restrict__ b_in,
                                               float* __restrict__ qbuf,
                                               float* __restrict__ out) {
  const int tt  = blockIdx.x;   // 0..31 (64-t tile)
  const int b   = blockIdx.y;   // 0..15
  const int tid = threadIdx.x;
  const int w   = tid >> 6;
  const int lane = tid & 63;
  const int t   = tt * 64 + lane;

  __shared__ float4 wl[1024];          // weight row -> (c0,c1,c2,c3)
  __shared__ double sacc[4][4][64];    // [wave][c][lane]

  for (int i = tid; i < 1024; i += 256) {
    const int g = i >> 9, d = i & 511;
    const float* wp = w_in + g * 2048 + d;
    wl[i] = make_float4(wp[0], wp[512], wp[1024], wp[1536]);
  }
  __syncthreads();

  const float* xp = x + ((size_t)b * DIMM + (size_t)w * 256) * TN + t;
  const int rb = w * 256;
  double a0 = 0.0, a1 = 0.0, a2 = 0.0, a3 = 0.0;
  #pragma unroll 8
  for (int r = 0; r < 256; ++r) {
    double xv = (double)xp[(size_t)r * TN];
    float4 wv = wl[rb + r];
    a0 += (double)wv.x * xv;
    a1 += (double)wv.y * xv;
    a2 += (double)wv.z * xv;
    a3 += (double)wv.w * xv;
  }
  sacc[w][0][lane] = a0;
  sacc[w][1][lane] = a1;
  sacc[w][2][lane] = a2;
  sacc[w][3][lane] = a3;
  __syncthreads();

  if (tid < 128) {
    const int g = w;  // 0 or 1
    const double half_l = (5.0 - 1.0) * (1.0 + 1e-3) / 2.0;  // match np expr
    const int basis[4] = {1, 5, 25, 125};
    float q[4];
    int idx0 = 0, idx1 = 0;
    #pragma unroll
    for (int c = 0; c < 4; ++c) {
      double z = sacc[2 * g][c][lane] + sacc[2 * g + 1][c][lane]
               + (double)b_in[g * 4 + c];
      double n0 = rint(tanh(z) * half_l);          // step 0, s=1
      double r1 = z - 0.5 * n0;
      double n1 = rint(tanh(4.0 * r1) * half_l);   // step 1, s=0.25
      q[c] = (float)(0.5 * n0 + 0.125 * n1);       // exact in f32
      idx0 += ((int)n0 + 2) * basis[c];
      idx1 += ((int)n1 + 2) * basis[c];
    }
    out[OUT_IND + ((size_t)b * 4 + g * 2 + 0) * TN + t] = (float)idx0;
    out[OUT_IND + ((size_t)b * 4 + g * 2 + 1) * TN + t] = (float)idx1;
    ((float4*)qbuf)[((size_t)b * TN + t) * 2 + g] = make_float4(q[0], q[1], q[2], q[3]);
  }
}

// ---------------------------------------------------------------------------
// K2: out-projection feat_t + perplexity.
//   dch 0..7: 128-dim x 512-t tile, float2 stores (write-bound path).
//   dch == 8 (b==0, tt=j): rebuild histogram j from the ind output written by
//   K1 (LDS float atomics, exact integer counts) and compute perplexity —
//   removes the global counts buffer and its zeroing dispatch entirely.
// ---------------------------------------------------------------------------
__global__ __launch_bounds__(256) void gfsq_k2(const float* __restrict__ qbuf,
                                               const float* __restrict__ w_out,
                                               const float* __restrict__ b_out,
                                               float* __restrict__ out) {
  const int dch = blockIdx.x;   // 0..7 feat; 8 = perplexity
  const int tt  = blockIdx.y;   // 0..3
  const int b   = blockIdx.z;   // 0..15
  const int tid = threadIdx.x;

  if (dch == 8) {
    if (b != 0) return;
    const int j = tt;  // codebook row 0..3
    __shared__ float  hist[NBINS];
    __shared__ double red[256];
    for (int i = tid; i < NBINS; i += 256) hist[i] = 0.0f;
    __syncthreads();
    for (int i = tid; i < BB * TN; i += 256) {
      const int b2 = i >> 11, t = i & 2047;
      const int v = (int)out[OUT_IND + ((size_t)b2 * 4 + j) * TN + t];
      atomicAdd(&hist[v], 1.0f);
    }
    __syncthreads();
    double s = 0.0;
    for (int i = tid; i < NBINS; i += 256) s += (double)hist[i];
    red[tid] = s;
    __syncthreads();
    for (int off = 128; off; off >>= 1) {
      if (tid < off) red[tid] += red[tid + off];
      __syncthreads();
    }
    const double tot = red[0] / 32768.0;  // == 1.0 exactly
    __syncthreads();
    double h = 0.0;
    for (int i = tid; i < NBINS; i += 256) {
      double e  = (double)hist[i] / 32768.0;
      double e2 = e / (tot + 1e-5);
      h += e2 * log(e2 + 1e-5);
    }
    red[tid] = h;
    __syncthreads();
    for (int off = 128; off; off >>= 1) {
      if (tid < off) red[tid] += red[tid + off];
      __syncthreads();
    }
    if (tid == 0) out[OUT_PERP + j] = (float)exp(-red[0]);
    if (j == 0 && tid < 4) out[OUT_ZERO + tid] = 0.0f;
    return;
  }

  // feat: block = (b, dims [dch*128, +128), t [tt*512, +512)), 2 t per thread
  __shared__ float4 wl[128];
  __shared__ float  bl[128];
  if (tid < 128) {
    wl[tid] = ((const float4*)w_out)[dch * 128 + tid];
    bl[tid] = b_out[dch * 128 + tid];
  }
  __syncthreads();

  const int g = dch >> 2;
  const int t = tt * 512 + tid * 2;
  const float4* qb = (const float4*)qbuf;
  const float4 qa = qb[((size_t)b * TN + t) * 2 + g];
  const float4 qc = qb[((size_t)b * TN + t + 1) * 2 + g];

  float* op = out + OUT_FEAT + ((size_t)b * DIMM + (size_t)dch * 128) * TN + t;
  #pragma unroll 4
  for (int dd = 0; dd < 128; ++dd) {
    float4 wv = wl[dd];
    float r0 = bl[dd] + wv.x * qa.x + wv.y * qa.y + wv.z * qa.z + wv.w * qa.w;
    float r1 = bl[dd] + wv.x * qc.x + wv.y * qc.y + wv.z * qc.z + wv.w * qc.w;
    *(float2*)(op + (size_t)dd * TN) = make_float2(r0, r1);
  }
}

// ---------------------------------------------------------------------------
extern "C" void kernel_launch(void* const* d_in, const int* in_sizes, int n_in,
                              void* d_out, int out_size, void* d_ws, size_t ws_size,
                              hipStream_t stream) {
  (void)in_sizes; (void)n_in; (void)out_size; (void)ws_size;

  const float* x     = (const float*)d_in[0];
  const float* w_in  = (const float*)d_in[1];
  const float* b_in  = (const float*)d_in[2];
  const float* w_out = (const float*)d_in[3];
  const float* b_out = (const float*)d_in[4];
  float* out  = (float*)d_out;
  float* qbuf = (float*)d_ws;   // 262144 floats

  gfsq_k1<<<dim3(32, 16), 256, 0, stream>>>(x, w_in, b_in, qbuf, out);
  gfsq_k2<<<dim3(9, 4, 16), 256, 0, stream>>>(qbuf, w_out, b_out, out);
}